// Round 1
// baseline (17.177 us; speedup 1.0000x reference)
//
#include <hip/hip_runtime.h>

// FlatDilation1D: out[j] = max_{k=0..200} ( x[j+k-100] + h[k] ),
//   h[k] = -((k-100)/scale)^16, out-of-range x treated as -inf (skipped).
// K_SIZE=201, HALF=100, ALPHA=16 (even -> repeated squaring, sign-safe).

#define K_SIZE 201
#define HALF   100

__global__ __launch_bounds__(256) void flat_dilation1d_kernel(
    const float* __restrict__ x,
    const float* __restrict__ scale_p,
    float* __restrict__ out)
{
    __shared__ float xs[K_SIZE];
    __shared__ float hs[K_SIZE];

    const int t = threadIdx.x;
    const float inv_scale = 1.0f / scale_p[0];

    if (t < K_SIZE) {
        xs[t] = x[t];
        float z = (float)(t - HALF) * inv_scale;
        float s = z * z;   // ^2
        s = s * s;         // ^4
        s = s * s;         // ^8
        s = s * s;         // ^16
        hs[t] = -s;
    }
    __syncthreads();

    if (t < K_SIZE) {
        // valid k: x-index t + k - HALF in [0, K_SIZE-1]
        int klo = HALF - t;              if (klo < 0)        klo = 0;
        int khi = HALF - t + K_SIZE - 1; if (khi > K_SIZE-1) khi = K_SIZE - 1;
        float m = -INFINITY;
        #pragma unroll 4
        for (int k = klo; k <= khi; ++k) {
            m = fmaxf(m, xs[t + k - HALF] + hs[k]);
        }
        out[t] = m;
    }
}

extern "C" void kernel_launch(void* const* d_in, const int* in_sizes, int n_in,
                              void* d_out, int out_size, void* d_ws, size_t ws_size,
                              hipStream_t stream)
{
    const float* x     = (const float*)d_in[0];
    const float* scale = (const float*)d_in[1];
    float* out         = (float*)d_out;

    flat_dilation1d_kernel<<<1, 256, 0, stream>>>(x, scale, out);
}

// Round 2
// 10.035 us; speedup vs baseline: 1.7117x; 1.7117x over previous
//
#include <hip/hip_runtime.h>

// FlatDilation1D: out[j] = max_{k=0..200} ( x[j+k-100] + h[k] ),
//   h[k] = -((k-100)/scale)^16, out-of-range x treated as -inf (skipped).
// K_SIZE=201, HALF=100, ALPHA=16 (even power -> repeated squaring).
//
// One wave (64 lanes) per output j. Each lane handles k = lane + 64*i
// (i = 0..3, predicated), computes x[j+k-100] - ((k-100)/scale)^16 in
// registers, then a 6-step shfl_xor max reduction. No LDS, no barriers.

#define K_SIZE 201
#define HALF   100

__global__ __launch_bounds__(64) void flat_dilation1d_kernel(
    const float* __restrict__ x,
    const float* __restrict__ scale_p,
    float* __restrict__ out)
{
    const int j    = blockIdx.x;    // output index, 0..200
    const int lane = threadIdx.x;   // 0..63

    const float inv_scale = 1.0f / scale_p[0];

    float m = -INFINITY;
    #pragma unroll
    for (int i = 0; i < 4; ++i) {
        const int k = lane + 64 * i;          // window index
        const int xi = j + k - HALF;          // x index
        if (k < K_SIZE && xi >= 0 && xi < K_SIZE) {
            const float z = (float)(k - HALF) * inv_scale;
            float s = z * z;   // ^2
            s = s * s;         // ^4
            s = s * s;         // ^8
            s = s * s;         // ^16
            m = fmaxf(m, x[xi] - s);
        }
    }

    // full-wave max reduction (64 lanes)
    #pragma unroll
    for (int off = 32; off > 0; off >>= 1) {
        m = fmaxf(m, __shfl_xor(m, off));
    }

    if (lane == 0) out[j] = m;
}

extern "C" void kernel_launch(void* const* d_in, const int* in_sizes, int n_in,
                              void* d_out, int out_size, void* d_ws, size_t ws_size,
                              hipStream_t stream)
{
    const float* x     = (const float*)d_in[0];
    const float* scale = (const float*)d_in[1];
    float* out         = (float*)d_out;

    flat_dilation1d_kernel<<<K_SIZE, 64, 0, stream>>>(x, scale, out);
}

// Round 3
// 9.629 us; speedup vs baseline: 1.7839x; 1.0422x over previous
//
#include <hip/hip_runtime.h>

// FlatDilation1D: out[j] = max_{k=0..200} ( x[j+k-100] + h[k] ),
//   h[k] = -((k-100)/scale)^16, out-of-range x skipped (treated as -inf).
// K_SIZE=201, HALF=100, ALPHA=16 (even power -> repeated squaring).
//
// 16 lanes per output: block = 256 threads = 16 groups; grid = 13 blocks.
// Each lane covers k = (lane&15) + 16*i, i=0..12 (independent loads, ILP),
// then a 4-step shfl_xor (1/2/4/8 -> DPP-fast) max reduction within the
// 16-lane group. No LDS, no barriers, shallow cross-lane chain.

#define K_SIZE 201
#define HALF   100

__global__ __launch_bounds__(256) void flat_dilation1d_kernel(
    const float* __restrict__ x,
    const float* __restrict__ scale_p,
    float* __restrict__ out)
{
    const int t     = threadIdx.x;
    const int group = t >> 4;            // 0..15 within block
    const int l     = t & 15;            // lane within group
    const int j     = blockIdx.x * 16 + group;   // output index

    const float inv_scale = 1.0f / scale_p[0];

    float m = -INFINITY;
    #pragma unroll
    for (int i = 0; i < 13; ++i) {
        const int k  = l + 16 * i;       // window index, 0..207
        const int xi = j + k - HALF;     // x index
        if (k < K_SIZE && j < K_SIZE && xi >= 0 && xi < K_SIZE) {
            const float z = (float)(k - HALF) * inv_scale;
            float s = z * z;   // ^2
            s = s * s;         // ^4
            s = s * s;         // ^8
            s = s * s;         // ^16
            m = fmaxf(m, x[xi] - s);
        }
    }

    // 16-lane max reduction: xor offsets 8,4,2,1 stay within the group
    #pragma unroll
    for (int off = 8; off > 0; off >>= 1) {
        m = fmaxf(m, __shfl_xor(m, off));
    }

    if (l == 0 && j < K_SIZE) out[j] = m;
}

extern "C" void kernel_launch(void* const* d_in, const int* in_sizes, int n_in,
                              void* d_out, int out_size, void* d_ws, size_t ws_size,
                              hipStream_t stream)
{
    const float* x     = (const float*)d_in[0];
    const float* scale = (const float*)d_in[1];
    float* out         = (float*)d_out;

    flat_dilation1d_kernel<<<(K_SIZE + 15) / 16, 256, 0, stream>>>(x, scale, out);
}